// Round 1
// baseline (9074.825 us; speedup 1.0000x reference)
//
#include <hip/hip_runtime.h>

#define T_LEN 2048

typedef _Float16 f16x8 __attribute__((ext_vector_type(8)));
typedef float f32x4 __attribute__((ext_vector_type(4)));

__device__ __forceinline__ float sigm(float v) { return 1.f / (1.f + __expf(-v)); }
__device__ __forceinline__ float tanh_f(float v) {
  v = fminf(fmaxf(v, -15.f), 15.f);
  float e = __expf(2.f * v);
  return (e - 1.f) / (e + 1.f);
}

// XOR-swizzled address into the A tile: [16 rows (seq)][512 k] f16.
// row stride = 1024B (16-way bank alias) -> xor bits 4..6 with row&7 (2-way, free).
__device__ __forceinline__ void* swzA(_Float16* base, int row, int khalf) {
  int byte = row * 1024 + khalf * 2;   // khalf multiple of 8 -> 16B aligned
  byte ^= (row & 7) << 4;
  return (void*)((char*)base + byte);
}

// Grid: 32 WGs x 256 threads.
//   group g = blockIdx&3 : {dir = g>>1, batch half = g&1} -> 16 sequences
//   member m = blockIdx>>2 : owns h-dims [32m..32m+31] (gate cols p*256+32m+..)
//   wave w (0..3) = gate part p in {i,j,f,o}; holds W[:, p*256+32m .. +31] in VGPRs.
__global__ __launch_bounds__(256, 1) void bilstm_kernel(
    const float* __restrict__ x, const float* __restrict__ Wfw,
    const float* __restrict__ bfw, const float* __restrict__ Wbw,
    const float* __restrict__ bbw, float* __restrict__ out,
    unsigned int* __restrict__ hglob, int* __restrict__ flags) {
  const int g = blockIdx.x & 3;
  const int m = blockIdx.x >> 2;
  const int dir = g >> 1, bh = g & 1;
  const int tid = threadIdx.x;
  const int w = tid >> 6;
  const int lane = tid & 63;
  const int l15 = lane & 15, l4 = lane >> 4;

  const float* W = dir ? Wbw : Wfw;
  const float* bias = dir ? bbw : bfw;

  __shared__ _Float16 Alds[16 * 512];  // 16KB, swizzled [seq][k]  (k<256: x, k>=256: h)
  __shared__ float Glds[4 * 16 * 32];  // 8KB gates [part][seq][dim32]

  // ---- load this wave's weight slice into B-fragments (registers) ----
  // B-frag layout (16x16x32): lane l holds B[k = 8*(l/16)+j][col = l%16], j=0..7
  f16x8 wB[2][16];
  {
    const int gc_base = w * 256 + m * 32;
#pragma unroll
    for (int n = 0; n < 2; ++n) {
#pragma unroll
      for (int kk = 0; kk < 16; ++kk) {
        const int gc = gc_base + n * 16 + l15;
        const int kb = kk * 32 + l4 * 8;
        f16x8 h;
#pragma unroll
        for (int j = 0; j < 8; ++j) h[j] = (_Float16)W[(kb + j) * 1024 + gc];
        wB[n][kk] = h;
      }
    }
  }

  // elementwise-phase mapping: thread -> (seq es, local dims ed, ed+1)
  const int es = tid >> 4;
  const int ed = (tid & 15) * 2;
  const int dglob = m * 32 + ed;
  float c0 = 0.f, c1 = 0.f;
  const float bi0 = bias[0 * 256 + dglob], bi1 = bias[0 * 256 + dglob + 1];
  const float bj0 = bias[1 * 256 + dglob], bj1 = bias[1 * 256 + dglob + 1];
  const float bf0 = bias[2 * 256 + dglob], bf1 = bias[2 * 256 + dglob + 1];
  const float bo0 = bias[3 * 256 + dglob], bo1 = bias[3 * 256 + dglob + 1];

  // staging mapping: thread -> (seq ss, k offset sk)
  const int ss = tid >> 4;
  const int sk = (tid & 15) * 16;

  int* Fbase = flags + g * 16;                       // [2 bufs][8 members]
  unsigned int* Hbase = hglob + g * 2 * 16 * 128;    // u32 units: [2][16 seq][128]

  for (int t = 0; t < T_LEN; ++t) {
    const int tx = dir ? (T_LEN - 1 - t) : t;
    const int wb = t & 1, rb = wb ^ 1;

    // issue x loads early (overlap with spin)
    const f32x4* xp =
        (const f32x4*)(x + (((bh * 16 + ss) * T_LEN + tx) << 8) + sk);
    f32x4 xv0 = xp[0], xv1 = xp[1], xv2 = xp[2], xv3 = xp[3];

    // ---- h_{t-1}: spin on peers' flags, then read and stage to LDS ----
    if (t > 0) {
      int* F = Fbase + rb * 8;
      for (;;) {
        int v = __hip_atomic_load(F + (lane & 7), __ATOMIC_RELAXED,
                                  __HIP_MEMORY_SCOPE_AGENT);
        if (__all(v >= t)) break;
      }
      (void)__hip_atomic_load(F + (lane & 7), __ATOMIC_ACQUIRE,
                              __HIP_MEMORY_SCOPE_AGENT);
      asm volatile("" ::: "memory");
      unsigned int hv[8];
      const unsigned int* hp = Hbase + (rb * 16 + ss) * 128 + (sk >> 1);
#pragma unroll
      for (int j = 0; j < 8; ++j)
        hv[j] = __hip_atomic_load(hp + j, __ATOMIC_RELAXED,
                                  __HIP_MEMORY_SCOPE_AGENT);
      uint4 q0 = {hv[0], hv[1], hv[2], hv[3]};
      uint4 q1 = {hv[4], hv[5], hv[6], hv[7]};
      *(uint4*)swzA(Alds, ss, 256 + sk) = q0;
      *(uint4*)swzA(Alds, ss, 256 + sk + 8) = q1;
    } else {
      uint4 z = {0u, 0u, 0u, 0u};
      *(uint4*)swzA(Alds, ss, 256 + sk) = z;
      *(uint4*)swzA(Alds, ss, 256 + sk + 8) = z;
    }

    // ---- x: convert to f16, stage to LDS ----
    {
      union {
        _Float16 h[16];
        uint4 q[2];
      } u;
#pragma unroll
      for (int j = 0; j < 4; ++j) {
        u.h[j] = (_Float16)xv0[j];
        u.h[4 + j] = (_Float16)xv1[j];
        u.h[8 + j] = (_Float16)xv2[j];
        u.h[12 + j] = (_Float16)xv3[j];
      }
      *(uint4*)swzA(Alds, ss, sk) = u.q[0];
      *(uint4*)swzA(Alds, ss, sk + 8) = u.q[1];
    }
    __syncthreads();

    // ---- MFMA: gates[16 seq x 32 cols] = [x|h] @ Wslice ----
    f32x4 acc0 = {0.f, 0.f, 0.f, 0.f}, acc1 = {0.f, 0.f, 0.f, 0.f};
#pragma unroll
    for (int kk = 0; kk < 16; ++kk) {
      f16x8 a = *(const f16x8*)swzA(Alds, l15, kk * 32 + l4 * 8);
      acc0 = __builtin_amdgcn_mfma_f32_16x16x32_f16(a, wB[0][kk], acc0, 0, 0, 0);
      acc1 = __builtin_amdgcn_mfma_f32_16x16x32_f16(a, wB[1][kk], acc1, 0, 0, 0);
    }
    // C/D layout: col = lane&15, row(seq) = 4*(lane>>4)+v
#pragma unroll
    for (int v = 0; v < 4; ++v) {
      Glds[w * 512 + (l4 * 4 + v) * 32 + l15] = acc0[v];
      Glds[w * 512 + (l4 * 4 + v) * 32 + 16 + l15] = acc1[v];
    }
    __syncthreads();

    // ---- elementwise LSTM cell (f32 state) ----
    const float* Gp = Glds + es * 32 + ed;
    float i0 = Gp[0 * 512] + bi0, i1 = Gp[0 * 512 + 1] + bi1;
    float j0 = Gp[1 * 512] + bj0, j1 = Gp[1 * 512 + 1] + bj1;
    float f0 = Gp[2 * 512] + bf0, f1 = Gp[2 * 512 + 1] + bf1;
    float o0 = Gp[3 * 512] + bo0, o1 = Gp[3 * 512 + 1] + bo1;
    c0 = c0 * sigm(f0 + 1.f) + sigm(i0) * tanh_f(j0);
    c1 = c1 * sigm(f1 + 1.f) + sigm(i1) * tanh_f(j1);
    float h0 = tanh_f(c0) * sigm(o0);
    float h1 = tanh_f(c1) * sigm(o1);

    // output (streaming store; out fully overwritten each launch)
    float* op = out + (((bh * 16 + es) * T_LEN + tx) << 9) + dir * 256 + dglob;
    __builtin_nontemporal_store(h0, op);
    __builtin_nontemporal_store(h1, op + 1);

    // publish h (device-scope u32, bypasses XCD L2 -> MALL-coherent)
    union {
      _Float16 hh[2];
      unsigned int u;
    } pk;
    pk.hh[0] = (_Float16)h0;
    pk.hh[1] = (_Float16)h1;
    __hip_atomic_store(Hbase + (wb * 16 + es) * 128 + (dglob >> 1), pk.u,
                       __ATOMIC_RELAXED, __HIP_MEMORY_SCOPE_AGENT);

    __syncthreads();  // drains vmcnt for all waves' stores before flag post
    if (tid == 0)
      __hip_atomic_store(Fbase + wb * 8 + m, t + 1, __ATOMIC_RELEASE,
                         __HIP_MEMORY_SCOPE_AGENT);
  }
}

extern "C" void kernel_launch(void* const* d_in, const int* in_sizes, int n_in,
                              void* d_out, int out_size, void* d_ws,
                              size_t ws_size, hipStream_t stream) {
  const float* x = (const float*)d_in[0];
  const float* Wfw = (const float*)d_in[1];
  const float* bfw = (const float*)d_in[2];
  const float* Wbw = (const float*)d_in[3];
  const float* bbw = (const float*)d_in[4];
  float* out = (float*)d_out;

  // ws layout: [0,64KB) h exchange (4 groups x 2 bufs x 16 seq x 256 f16),
  //            [64KB, +256B) flags (4 x 2 x 8 int)
  unsigned int* hglob = (unsigned int*)d_ws;
  int* flags = (int*)((char*)d_ws + 64 * 1024);
  hipMemsetAsync(flags, 0, 4 * 2 * 8 * sizeof(int), stream);

  bilstm_kernel<<<dim3(32), dim3(256), 0, stream>>>(x, Wfw, bfw, Wbw, bbw, out,
                                                    hglob, flags);
}

// Round 3
// 4955.042 us; speedup vs baseline: 1.8314x; 1.8314x over previous
//
#include <hip/hip_runtime.h>

#define T_LEN 2048

typedef _Float16 f16x8 __attribute__((ext_vector_type(8)));
typedef float f32x4 __attribute__((ext_vector_type(4)));
typedef float f32x2 __attribute__((ext_vector_type(2)));
typedef unsigned long long u64;

__device__ __forceinline__ float sigm(float v) { return 1.f / (1.f + __expf(-v)); }
__device__ __forceinline__ float tanh_f(float v) {
  v = fminf(fmaxf(v, -15.f), 15.f);
  float e = __expf(2.f * v);
  return (e - 1.f) / (e + 1.f);
}

// XOR-swizzled address into the A tile: [16 rows (seq)][512 k] f16.
// row stride = 1024B (16-way bank alias) -> xor bits 4..6 with row&7 (2-way, free).
__device__ __forceinline__ void* swzA(_Float16* base, int row, int khalf) {
  int byte = row * 1024 + khalf * 2;  // khalf multiple of 8 -> 16B aligned
  byte ^= (row & 7) << 4;
  return (void*)((char*)base + byte);
}

// Grid: 32 WGs x 256 threads.
//   group g = blockIdx&3 : {dir = g>>1, batch half = g&1} -> 16 sequences
//   member m = blockIdx>>2 : owns h-dims [32m..32m+31]
//   wave w (0..3) = gate part p in {i,j,f,o}; W[:, p*256+32m..+31] in VGPRs.
// Exchange: u64 lines {lo=2xf16 h, hi=stamp t+1}, double-buffered by t&1,
// agent-scope relaxed atomics (MALL-coherent). No flags, no fences.
__global__ __launch_bounds__(256, 1) void bilstm_kernel(
    const float* __restrict__ x, const float* __restrict__ Wfw,
    const float* __restrict__ bfw, const float* __restrict__ Wbw,
    const float* __restrict__ bbw, float* __restrict__ out,
    u64* __restrict__ hglob) {
  const int g = blockIdx.x & 3;
  const int m = blockIdx.x >> 2;
  const int dir = g >> 1, bh = g & 1;
  const int tid = threadIdx.x;
  const int w = tid >> 6;
  const int lane = tid & 63;
  const int l15 = lane & 15, l4 = lane >> 4;

  const float* W = dir ? Wbw : Wfw;
  const float* bias = dir ? bbw : bfw;

  __shared__ _Float16 Alds[16 * 512];   // 16KB swizzled [seq][k] (k<256 x, k>=256 h)
  __shared__ float Glds[4 * 16 * 34];   // gates, stride 34 (bank-conflict-free)

  // ---- weight slice -> B fragments (regs). lane l holds B[k=8*(l/16)+j][col=l%16]
  f16x8 wB[2][16];
  {
    const int gc_base = w * 256 + m * 32;
#pragma unroll
    for (int n = 0; n < 2; ++n) {
#pragma unroll
      for (int kk = 0; kk < 16; ++kk) {
        const int gc = gc_base + n * 16 + l15;
        const int kb = kk * 32 + l4 * 8;
        f16x8 h;
#pragma unroll
        for (int j = 0; j < 8; ++j) h[j] = (_Float16)W[(kb + j) * 1024 + gc];
        wB[n][kk] = h;
      }
    }
  }

  // elementwise mapping: thread -> (seq es, dims dglob, dglob+1)
  const int es = tid >> 4;
  const int ed = (tid & 15) * 2;
  const int dglob = m * 32 + ed;
  float c0 = 0.f, c1 = 0.f;
  const float bi0 = bias[0 * 256 + dglob], bi1 = bias[0 * 256 + dglob + 1];
  const float bj0 = bias[1 * 256 + dglob], bj1 = bias[1 * 256 + dglob + 1];
  const float bf0 = bias[2 * 256 + dglob], bf1 = bias[2 * 256 + dglob + 1];
  const float bo0 = bias[3 * 256 + dglob], bo1 = bias[3 * 256 + dglob + 1];

  // staging mapping: thread -> (seq ss, k offset sk)
  const int ss = tid >> 4;
  const int sk = (tid & 15) * 16;

  // exchange region for this group: u64 [2 buf][16 seq][128 dim-pairs]
  u64* Hg = hglob + (u64)g * (2 * 16 * 128);
  u64* my_slot0 = Hg + (0 * 16 + es) * 128 + (dglob >> 1);
  u64* my_slot1 = Hg + (1 * 16 + es) * 128 + (dglob >> 1);

  // prologue: h_{-1} = 0 staged once; prefetch x_0
  {
    uint4 z = {0u, 0u, 0u, 0u};
    *(uint4*)swzA(Alds, ss, 256 + sk) = z;
    *(uint4*)swzA(Alds, ss, 256 + sk + 8) = z;
  }
  const int tx0 = dir ? (T_LEN - 1) : 0;
  const f32x4* xp0 = (const f32x4*)(x + (((bh * 16 + ss) * T_LEN + tx0) << 8) + sk);
  f32x4 xv0 = xp0[0], xv1 = xp0[1], xv2 = xp0[2], xv3 = xp0[3];

  for (int t = 0; t < T_LEN; ++t) {
    const int tx = dir ? (T_LEN - 1 - t) : t;

    // ---- stage x_t (from prefetch regs) as f16 into A x-half ----
    {
      union { _Float16 h[16]; uint4 q[2]; } u;
#pragma unroll
      for (int j = 0; j < 4; ++j) {
        u.h[j] = (_Float16)xv0[j];
        u.h[4 + j] = (_Float16)xv1[j];
        u.h[8 + j] = (_Float16)xv2[j];
        u.h[12 + j] = (_Float16)xv3[j];
      }
      *(uint4*)swzA(Alds, ss, sk) = u.q[0];
      *(uint4*)swzA(Alds, ss, sk + 8) = u.q[1];
    }
    __syncthreads();  // B1: x staged (also orders vs prev step's Glds/A reads)

    // ---- prefetch x_{t+1} (latency leaves the critical chain) ----
    {
      const int tn = (t + 1 < T_LEN) ? t + 1 : t;
      const int txn = dir ? (T_LEN - 1 - tn) : tn;
      const f32x4* xp =
          (const f32x4*)(x + (((bh * 16 + ss) * T_LEN + txn) << 8) + sk);
      xv0 = xp[0]; xv1 = xp[1]; xv2 = xp[2]; xv3 = xp[3];
    }

    // ---- x-half MFMAs (K 0..255) — fills the h-wait window ----
    f32x4 acc0 = {0.f, 0.f, 0.f, 0.f}, acc1 = {0.f, 0.f, 0.f, 0.f};
#pragma unroll
    for (int kk = 0; kk < 8; ++kk) {
      f16x8 a = *(const f16x8*)swzA(Alds, l15, kk * 32 + l4 * 8);
      acc0 = __builtin_amdgcn_mfma_f32_16x16x32_f16(a, wB[0][kk], acc0, 0, 0, 0);
      acc1 = __builtin_amdgcn_mfma_f32_16x16x32_f16(a, wB[1][kk], acc1, 0, 0, 0);
    }

    // ---- poll peers' stamped h lines (single-hop), stage A h-half ----
    if (t > 0) {
      const u64* hp = Hg + (((t - 1) & 1) * 16 + ss) * 128 + (sk >> 1);
      u64 q[8];
      for (;;) {
#pragma unroll
        for (int j = 0; j < 8; ++j)
          q[j] = __hip_atomic_load(hp + j, __ATOMIC_RELAXED,
                                   __HIP_MEMORY_SCOPE_AGENT);
        bool ok = true;
#pragma unroll
        for (int j = 0; j < 8; ++j)
          ok &= ((unsigned int)(q[j] >> 32) == (unsigned int)t);
        if (__all(ok)) break;
      }
      uint4 q0 = {(unsigned)q[0], (unsigned)q[1], (unsigned)q[2], (unsigned)q[3]};
      uint4 q1 = {(unsigned)q[4], (unsigned)q[5], (unsigned)q[6], (unsigned)q[7]};
      *(uint4*)swzA(Alds, ss, 256 + sk) = q0;
      *(uint4*)swzA(Alds, ss, 256 + sk + 8) = q1;
    }
    __syncthreads();  // B2: h staged

    // ---- h-half MFMAs (K 256..511) ----
#pragma unroll
    for (int kk = 8; kk < 16; ++kk) {
      f16x8 a = *(const f16x8*)swzA(Alds, l15, kk * 32 + l4 * 8);
      acc0 = __builtin_amdgcn_mfma_f32_16x16x32_f16(a, wB[0][kk], acc0, 0, 0, 0);
      acc1 = __builtin_amdgcn_mfma_f32_16x16x32_f16(a, wB[1][kk], acc1, 0, 0, 0);
    }

    // ---- gates -> LDS (stride 34: <=2-way bank alias, free) ----
    {
      float* gw = Glds + w * 544 + l15;
      const int r = l4 * 4;
#pragma unroll
      for (int v = 0; v < 4; ++v) {
        gw[(r + v) * 34] = acc0[v];
        gw[(r + v) * 34 + 16] = acc1[v];
      }
    }
    __syncthreads();  // B3: gates ready

    // ---- LSTM cell (f32 state) ----
    const float* Gp = Glds + es * 34 + ed;
    f32x2 gi = *(const f32x2*)(Gp + 0 * 544);
    f32x2 gj = *(const f32x2*)(Gp + 1 * 544);
    f32x2 gf = *(const f32x2*)(Gp + 2 * 544);
    f32x2 go = *(const f32x2*)(Gp + 3 * 544);
    c0 = c0 * sigm(gf[0] + bf0 + 1.f) + sigm(gi[0] + bi0) * tanh_f(gj[0] + bj0);
    c1 = c1 * sigm(gf[1] + bf1 + 1.f) + sigm(gi[1] + bi1) * tanh_f(gj[1] + bj1);
    float h0 = tanh_f(c0) * sigm(go[0] + bo0);
    float h1 = tanh_f(c1) * sigm(go[1] + bo1);

    // ---- publish h FIRST (critical path), then output store ----
    union { _Float16 hh[2]; unsigned int u; } pk;
    pk.hh[0] = (_Float16)h0;
    pk.hh[1] = (_Float16)h1;
    u64 pay = ((u64)(unsigned int)(t + 1) << 32) | (u64)pk.u;
    __hip_atomic_store((t & 1) ? my_slot1 : my_slot0, pay, __ATOMIC_RELAXED,
                       __HIP_MEMORY_SCOPE_AGENT);

    f32x2 hv = {h0, h1};
    __builtin_nontemporal_store(
        hv, (f32x2*)(out + (((bh * 16 + es) * T_LEN + tx) << 9) + dir * 256 + dglob));
  }
}

extern "C" void kernel_launch(void* const* d_in, const int* in_sizes, int n_in,
                              void* d_out, int out_size, void* d_ws,
                              size_t ws_size, hipStream_t stream) {
  const float* x = (const float*)d_in[0];
  const float* Wfw = (const float*)d_in[1];
  const float* bfw = (const float*)d_in[2];
  const float* Wbw = (const float*)d_in[3];
  const float* bbw = (const float*)d_in[4];
  float* out = (float*)d_out;

  // ws: [0, 128KB) stamped h-exchange: 4 groups x 2 bufs x 16 seq x 128 u64
  u64* hglob = (u64*)d_ws;
  (void)hipMemsetAsync(hglob, 0, 4 * 2 * 16 * 128 * sizeof(u64), stream);

  bilstm_kernel<<<dim3(32), dim3(256), 0, stream>>>(x, Wfw, bfw, Wbw, bbw, out,
                                                    hglob);
}